// Round 1
// baseline (569.319 us; speedup 1.0000x reference)
//
#include <hip/hip_runtime.h>
#include <cstdint>

constexpr int Bb = 8, Hh = 512, Ww = 512;
constexpr int HWn = Hh * Ww;          // 262144
constexpr int CH = 32;                // rows per block in vertical passes

__device__ __forceinline__ int reflect_idx(int p, int n) {
    p = (p < 0) ? -p : p;
    return (p < n) ? p : (2 * n - 2 - p);
}

__device__ __forceinline__ int clamp_r(const int* rad) {
    int r = rad[0];
    return (r < 1) ? 1 : ((r > 50) ? 50 : r);
}

// K1: per-row — compute t0 (rows i-1,i), tg row i, gray row i in LDS, then
// horizontal box sums of {gray, tg, gray*tg, gray^2} with reflect padding.
__global__ __launch_bounds__(512) void k1_stats_h(
    const float* __restrict__ img, const float* __restrict__ omega,
    const float* __restrict__ atm, const int* __restrict__ rad,
    float* __restrict__ gray_out,
    float* __restrict__ h1, float* __restrict__ h2,
    float* __restrict__ h3, float* __restrict__ h4)
{
    const int i = blockIdx.x;
    const int b = blockIdx.y;
    const int j = threadIdx.x;           // 512 threads = one per column
    const int r = clamp_r(rad);

    __shared__ float t0c[512], t0p[512], gr[512], tg[512];

    const float om = omega[b];
    const float iA0 = 1.0f / (atm[b*3+0] + 1e-8f);
    const float iA1 = 1.0f / (atm[b*3+1] + 1e-8f);
    const float iA2 = 1.0f / (atm[b*3+2] + 1e-8f);
    const float* imb = img + (size_t)b * 3 * HWn;
    const int ip = (i > 0) ? (i - 1) : 0;

    // current row i
    float r0 = imb[0*HWn + i*Ww + j];
    float g0 = imb[1*HWn + i*Ww + j];
    float b0 = imb[2*HWn + i*Ww + j];
    float dark = fminf(fminf(r0*iA0, g0*iA1), b0*iA2);
    t0c[j] = 1.0f - om * dark;
    // previous row (== row 0 when i==0)
    float r1 = imb[0*HWn + ip*Ww + j];
    float g1 = imb[1*HWn + ip*Ww + j];
    float b1 = imb[2*HWn + ip*Ww + j];
    float dark1 = fminf(fminf(r1*iA0, g1*iA1), b1*iA2);
    t0p[j] = 1.0f - om * dark1;
    gr[j] = 0.299f*r0 + 0.587f*g0 + 0.114f*b0;
    __syncthreads();

    // tx on row (i-1 for i>0, else row 0), then wy applied for i>0
    float tx;
    if (j == 0) tx = t0p[0];
    else        tx = t0p[j-1] * __expf(-fabsf(t0p[j] - t0p[j-1]));
    float tgv = (i == 0) ? tx : tx * __expf(-fabsf(t0c[j] - t0p[j]));
    tg[j] = tgv;
    __syncthreads();

    float sg = 0.f, st = 0.f, sgt = 0.f, sgg = 0.f;
    for (int d = -r; d <= r; ++d) {
        int m = reflect_idx(j + d, Ww);
        float g = gr[m], t = tg[m];
        sg += g; st += t; sgt += g * t; sgg += g * g;
    }
    size_t o = (size_t)b * HWn + (size_t)i * Ww + j;
    gray_out[o] = gr[j];
    h1[o] = sg; h2[o] = st; h3[o] = sgt; h4[o] = sgg;
}

// K2: vertical sliding-window box on 4 horizontal-sum fields -> a,b
__global__ __launch_bounds__(512) void k2_stats_v(
    const float* __restrict__ h1, const float* __restrict__ h2,
    const float* __restrict__ h3, const float* __restrict__ h4,
    const int* __restrict__ rad,
    float* __restrict__ a_out, float* __restrict__ b_out)
{
    const int b = blockIdx.y;
    const int y0 = blockIdx.x * CH;
    const int j = threadIdx.x;
    const int r = clamp_r(rad);
    const float inv_kk = 1.0f / (float)((2*r+1) * (2*r+1));
    const size_t base = (size_t)b * HWn + j;

    float s1 = 0.f, s2 = 0.f, s3 = 0.f, s4 = 0.f;
    for (int d = -r; d <= r; ++d) {
        int m = reflect_idx(y0 + d, Hh);
        size_t o = base + (size_t)m * Ww;
        s1 += h1[o]; s2 += h2[o]; s3 += h3[o]; s4 += h4[o];
    }
    for (int y = y0; y < y0 + CH; ++y) {
        float mI  = s1 * inv_kk;
        float mp  = s2 * inv_kk;
        float mIp = s3 * inv_kk;
        float mII = s4 * inv_kk;
        float cov = mIp - mI * mp;
        float var = mII - mI * mI;
        float av  = cov / (var + 0.5f);
        float bv  = mp - av * mI;
        size_t o = base + (size_t)y * Ww;
        a_out[o] = av; b_out[o] = bv;
        int yin  = reflect_idx(y + 1 + r, Hh);
        int yout = reflect_idx(y - r, Hh);
        size_t oi = base + (size_t)yin * Ww, oo = base + (size_t)yout * Ww;
        s1 += h1[oi] - h1[oo];
        s2 += h2[oi] - h2[oo];
        s3 += h3[oi] - h3[oo];
        s4 += h4[oi] - h4[oo];
    }
}

// K3: horizontal box sums of a,b
__global__ __launch_bounds__(512) void k3_ab_h(
    const float* __restrict__ a_in, const float* __restrict__ b_in,
    const int* __restrict__ rad,
    float* __restrict__ ha, float* __restrict__ hb)
{
    const int i = blockIdx.x;
    const int b = blockIdx.y;
    const int j = threadIdx.x;
    const int r = clamp_r(rad);
    __shared__ float sa[512], sb[512];
    size_t o = (size_t)b * HWn + (size_t)i * Ww + j;
    sa[j] = a_in[o]; sb[j] = b_in[o];
    __syncthreads();
    float s1 = 0.f, s2 = 0.f;
    for (int d = -r; d <= r; ++d) {
        int m = reflect_idx(j + d, Ww);
        s1 += sa[m]; s2 += sb[m];
    }
    ha[o] = s1; hb[o] = s2;
}

// K4: vertical box on ha,hb -> t_final -> J (written to d_out, all 3 channels)
__global__ __launch_bounds__(512) void k4_final_v(
    const float* __restrict__ ha, const float* __restrict__ hb,
    const float* __restrict__ gray, const float* __restrict__ img,
    const float* __restrict__ atm, const int* __restrict__ rad,
    float* __restrict__ J)
{
    const int b = blockIdx.y;
    const int y0 = blockIdx.x * CH;
    const int j = threadIdx.x;
    const int r = clamp_r(rad);
    const float inv_kk = 1.0f / (float)((2*r+1) * (2*r+1));
    const float A0 = atm[b*3+0], A1 = atm[b*3+1], A2 = atm[b*3+2];
    const size_t base = (size_t)b * HWn + j;
    const float* imb = img + (size_t)b * 3 * HWn;
    float* Jb = J + (size_t)b * 3 * HWn;

    float s1 = 0.f, s2 = 0.f;
    for (int d = -r; d <= r; ++d) {
        int m = reflect_idx(y0 + d, Hh);
        s1 += ha[base + (size_t)m * Ww];
        s2 += hb[base + (size_t)m * Ww];
    }
    for (int y = y0; y < y0 + CH; ++y) {
        size_t o = base + (size_t)y * Ww;
        float g = gray[o];
        float t = s1 * inv_kk * g + s2 * inv_kk;
        t = fminf(fmaxf(t, 0.1f), 1.0f);
        float invt = 1.0f / (t + 1e-8f);
        size_t po = (size_t)y * Ww + j;
        float v0 = (imb[0*HWn + po] - A0) * invt + A0;
        float v1 = (imb[1*HWn + po] - A1) * invt + A1;
        float v2 = (imb[2*HWn + po] - A2) * invt + A2;
        Jb[0*HWn + po] = fminf(fmaxf(v0, 0.f), 1.f);
        Jb[1*HWn + po] = fminf(fmaxf(v1, 0.f), 1.f);
        Jb[2*HWn + po] = fminf(fmaxf(v2, 0.f), 1.f);
        int yin  = reflect_idx(y + 1 + r, Hh);
        int yout = reflect_idx(y - r, Hh);
        s1 += ha[base + (size_t)yin * Ww] - ha[base + (size_t)yout * Ww];
        s2 += hb[base + (size_t)yin * Ww] - hb[base + (size_t)yout * Ww];
    }
}

// K5: exact k-th order statistic per (b,c) via MSB-first radix select.
// One block per (b,c); tracks both ranks (low/high percentile) simultaneously.
__global__ __launch_bounds__(1024) void k5_select(
    const float* __restrict__ J,
    const float* __restrict__ L_low, const float* __restrict__ L_high,
    float* __restrict__ p_low, float* __restrict__ p_high)
{
    const int bc = blockIdx.x;           // 0..23
    const int b = bc / 3;
    const int tid = threadIdx.x;
    const int n = HWn;
    const float* base = J + (size_t)bc * HWn;
    const unsigned int ONE = 0x3F800000u;

    __shared__ unsigned int hist[2][256];
    __shared__ unsigned int scan[2][256];
    __shared__ unsigned int sh_prefix[2];
    __shared__ int sh_k[2];

    if (tid == 0) {
        int k0 = (int)(L_low[b]  / 100.0f * (float)n);
        int k1 = (int)(L_high[b] / 100.0f * (float)n);
        k0 = (k0 < 0) ? 0 : ((k0 > n-1) ? n-1 : k0);
        k1 = (k1 < 0) ? 0 : ((k1 > n-1) ? n-1 : k1);
        sh_k[0] = k0; sh_k[1] = k1;
        sh_prefix[0] = 0u; sh_prefix[1] = 0u;
    }
    __syncthreads();

    for (int pass = 0; pass < 4; ++pass) {
        const int shift = 24 - 8 * pass;
        const unsigned int maskHigh = (pass == 0) ? 0u : (0xFFFFFFFFu << (shift + 8));
        if (tid < 512) ((unsigned int*)hist)[tid] = 0u;
        __syncthreads();
        const unsigned int p0 = sh_prefix[0], p1 = sh_prefix[1];

        unsigned int czero = 0, cone = 0;
        for (int idx = tid; idx < n; idx += 1024) {
            unsigned int key = __float_as_uint(base[idx]);
            if (key == 0u)      { czero++; continue; }
            if (key == ONE)     { cone++;  continue; }
            if ((key & maskHigh) == p0) atomicAdd(&hist[0][(key >> shift) & 255u], 1u);
            if ((key & maskHigh) == p1) atomicAdd(&hist[1][(key >> shift) & 255u], 1u);
        }
        if (czero) {
            if ((0u & maskHigh) == p0) atomicAdd(&hist[0][0], czero);
            if ((0u & maskHigh) == p1) atomicAdd(&hist[1][0], czero);
        }
        if (cone) {
            unsigned int bin = (ONE >> shift) & 255u;
            if ((ONE & maskHigh) == p0) atomicAdd(&hist[0][bin], cone);
            if ((ONE & maskHigh) == p1) atomicAdd(&hist[1][bin], cone);
        }
        __syncthreads();

        // inclusive scan over 256 bins, per target (threads 0..511)
        if (tid < 512) {
            int t = tid >> 8, lane = tid & 255;
            scan[t][lane] = hist[t][lane];
        }
        __syncthreads();
        for (int off = 1; off < 256; off <<= 1) {
            unsigned int v = 0;
            if (tid < 512) {
                int t = tid >> 8, lane = tid & 255;
                if (lane >= off) v = scan[t][lane - off];
            }
            __syncthreads();
            if (tid < 512) {
                int t = tid >> 8, lane = tid & 255;
                scan[t][lane] += v;
            }
            __syncthreads();
        }
        int kt = 0;
        if (tid < 512) kt = sh_k[tid >> 8];
        __syncthreads();
        if (tid < 512) {
            int t = tid >> 8, lane = tid & 255;
            unsigned int incl = scan[t][lane];
            unsigned int excl = (lane == 0) ? 0u : scan[t][lane - 1];
            if ((int)excl <= kt && kt < (int)incl) {
                sh_prefix[t] |= ((unsigned int)lane) << shift;
                sh_k[t] = kt - (int)excl;
            }
        }
        __syncthreads();
    }
    if (tid == 0) p_low[bc]  = __uint_as_float(sh_prefix[0]);
    if (tid == 1) p_high[bc] = __uint_as_float(sh_prefix[1]);
}

// K6: in-place percentile stretch on d_out
__global__ __launch_bounds__(256) void k6_norm(
    float* __restrict__ J,
    const float* __restrict__ p_low, const float* __restrict__ p_high)
{
    size_t idx = (size_t)blockIdx.x * 256 + threadIdx.x;
    int bc = (int)(idx >> 18);           // HWn == 2^18
    float pl = p_low[bc], ph = p_high[bc];
    float v = J[idx];
    v = fminf(fmaxf(v, pl), ph);
    v = (v - pl) / (ph - pl + 1e-8f);
    J[idx] = fminf(fmaxf(v, 0.f), 1.f);
}

extern "C" void kernel_launch(void* const* d_in, const int* in_sizes, int n_in,
                              void* d_out, int out_size, void* d_ws, size_t ws_size,
                              hipStream_t stream)
{
    const float* img    = (const float*)d_in[0];
    const float* omega  = (const float*)d_in[1];
    const float* atm    = (const float*)d_in[2];
    const float* L_low  = (const float*)d_in[3];
    const float* L_high = (const float*)d_in[4];
    const int*   rad    = (const int*)d_in[5];
    float* J  = (float*)d_out;
    float* ws = (float*)d_ws;

    const size_t F = (size_t)Bb * HWn;   // 2097152 floats per field
    float* gray = ws;
    float* h1 = ws + 1*F;
    float* h2 = ws + 2*F;
    float* h3 = ws + 3*F;
    float* h4 = ws + 4*F;
    float* a_ = ws + 5*F;
    float* b_ = ws + 6*F;
    float* ha = h1;   // reuse: h1..h4 dead after K2
    float* hb = h2;
    float* pl = ws + 7*F;
    float* ph = pl + 32;

    k1_stats_h<<<dim3(Hh, Bb), 512, 0, stream>>>(img, omega, atm, rad, gray, h1, h2, h3, h4);
    k2_stats_v<<<dim3(Hh/CH, Bb), 512, 0, stream>>>(h1, h2, h3, h4, rad, a_, b_);
    k3_ab_h  <<<dim3(Hh, Bb), 512, 0, stream>>>(a_, b_, rad, ha, hb);
    k4_final_v<<<dim3(Hh/CH, Bb), 512, 0, stream>>>(ha, hb, gray, img, atm, rad, J);
    k5_select<<<Bb*3, 1024, 0, stream>>>(J, L_low, L_high, pl, ph);
    k6_norm  <<<(int)(((size_t)Bb*3*HWn)/256), 256, 0, stream>>>(J, pl, ph);
}

// Round 2
// 230.601 us; speedup vs baseline: 2.4688x; 2.4688x over previous
//
#include <hip/hip_runtime.h>
#include <cstdint>

constexpr int Bb = 8, Hh = 512, Ww = 512;
constexpr int HWn = Hh * Ww;          // 262144 = 2^18
constexpr int CH = 32;                // rows per block in vertical passes
constexpr unsigned int ONEBITS = 0x3F800000u;
constexpr int NSUB = 32;              // sub-blocks per (b,c) in hist kernels

__device__ __forceinline__ int reflect_idx(int p, int n) {
    p = (p < 0) ? -p : p;
    return (p < n) ? p : (2 * n - 2 - p);
}

__device__ __forceinline__ int clamp_r(const int* rad) {
    int r = rad[0];
    return (r < 1) ? 1 : ((r > 50) ? 50 : r);
}

// K1: per-row — compute t0 (rows i-1,i), tg row i, gray row i in LDS, then
// horizontal box sums of {gray, tg, gray*tg, gray^2} with reflect padding.
__global__ __launch_bounds__(512) void k1_stats_h(
    const float* __restrict__ img, const float* __restrict__ omega,
    const float* __restrict__ atm, const int* __restrict__ rad,
    float* __restrict__ gray_out,
    float* __restrict__ h1, float* __restrict__ h2,
    float* __restrict__ h3, float* __restrict__ h4)
{
    const int i = blockIdx.x;
    const int b = blockIdx.y;
    const int j = threadIdx.x;           // 512 threads = one per column
    const int r = clamp_r(rad);

    __shared__ float t0c[512], t0p[512], gr[512], tg[512];

    const float om = omega[b];
    const float iA0 = 1.0f / (atm[b*3+0] + 1e-8f);
    const float iA1 = 1.0f / (atm[b*3+1] + 1e-8f);
    const float iA2 = 1.0f / (atm[b*3+2] + 1e-8f);
    const float* imb = img + (size_t)b * 3 * HWn;
    const int ip = (i > 0) ? (i - 1) : 0;

    float r0 = imb[0*HWn + i*Ww + j];
    float g0 = imb[1*HWn + i*Ww + j];
    float b0 = imb[2*HWn + i*Ww + j];
    float dark = fminf(fminf(r0*iA0, g0*iA1), b0*iA2);
    t0c[j] = 1.0f - om * dark;
    float r1 = imb[0*HWn + ip*Ww + j];
    float g1 = imb[1*HWn + ip*Ww + j];
    float b1 = imb[2*HWn + ip*Ww + j];
    float dark1 = fminf(fminf(r1*iA0, g1*iA1), b1*iA2);
    t0p[j] = 1.0f - om * dark1;
    gr[j] = 0.299f*r0 + 0.587f*g0 + 0.114f*b0;
    __syncthreads();

    float tx;
    if (j == 0) tx = t0p[0];
    else        tx = t0p[j-1] * __expf(-fabsf(t0p[j] - t0p[j-1]));
    float tgv = (i == 0) ? tx : tx * __expf(-fabsf(t0c[j] - t0p[j]));
    tg[j] = tgv;
    __syncthreads();

    float sg = 0.f, st = 0.f, sgt = 0.f, sgg = 0.f;
    for (int d = -r; d <= r; ++d) {
        int m = reflect_idx(j + d, Ww);
        float g = gr[m], t = tg[m];
        sg += g; st += t; sgt += g * t; sgg += g * g;
    }
    size_t o = (size_t)b * HWn + (size_t)i * Ww + j;
    gray_out[o] = gr[j];
    h1[o] = sg; h2[o] = st; h3[o] = sgt; h4[o] = sgg;
}

// K2: vertical sliding-window box on 4 horizontal-sum fields -> a,b
__global__ __launch_bounds__(512) void k2_stats_v(
    const float* __restrict__ h1, const float* __restrict__ h2,
    const float* __restrict__ h3, const float* __restrict__ h4,
    const int* __restrict__ rad,
    float* __restrict__ a_out, float* __restrict__ b_out)
{
    const int b = blockIdx.y;
    const int y0 = blockIdx.x * CH;
    const int j = threadIdx.x;
    const int r = clamp_r(rad);
    const float inv_kk = 1.0f / (float)((2*r+1) * (2*r+1));
    const size_t base = (size_t)b * HWn + j;

    float s1 = 0.f, s2 = 0.f, s3 = 0.f, s4 = 0.f;
    for (int d = -r; d <= r; ++d) {
        int m = reflect_idx(y0 + d, Hh);
        size_t o = base + (size_t)m * Ww;
        s1 += h1[o]; s2 += h2[o]; s3 += h3[o]; s4 += h4[o];
    }
    for (int y = y0; y < y0 + CH; ++y) {
        float mI  = s1 * inv_kk;
        float mp  = s2 * inv_kk;
        float mIp = s3 * inv_kk;
        float mII = s4 * inv_kk;
        float cov = mIp - mI * mp;
        float var = mII - mI * mI;
        float av  = cov / (var + 0.5f);
        float bv  = mp - av * mI;
        size_t o = base + (size_t)y * Ww;
        a_out[o] = av; b_out[o] = bv;
        int yin  = reflect_idx(y + 1 + r, Hh);
        int yout = reflect_idx(y - r, Hh);
        size_t oi = base + (size_t)yin * Ww, oo = base + (size_t)yout * Ww;
        s1 += h1[oi] - h1[oo];
        s2 += h2[oi] - h2[oo];
        s3 += h3[oi] - h3[oo];
        s4 += h4[oi] - h4[oo];
    }
}

// K3: horizontal box sums of a,b
__global__ __launch_bounds__(512) void k3_ab_h(
    const float* __restrict__ a_in, const float* __restrict__ b_in,
    const int* __restrict__ rad,
    float* __restrict__ ha, float* __restrict__ hb)
{
    const int i = blockIdx.x;
    const int b = blockIdx.y;
    const int j = threadIdx.x;
    const int r = clamp_r(rad);
    __shared__ float sa[512], sb[512];
    size_t o = (size_t)b * HWn + (size_t)i * Ww + j;
    sa[j] = a_in[o]; sb[j] = b_in[o];
    __syncthreads();
    float s1 = 0.f, s2 = 0.f;
    for (int d = -r; d <= r; ++d) {
        int m = reflect_idx(j + d, Ww);
        s1 += sa[m]; s2 += sb[m];
    }
    ha[o] = s1; hb[o] = s2;
}

// K4: vertical box on ha,hb -> t_final -> J (written to d_out, all 3 channels)
__global__ __launch_bounds__(512) void k4_final_v(
    const float* __restrict__ ha, const float* __restrict__ hb,
    const float* __restrict__ gray, const float* __restrict__ img,
    const float* __restrict__ atm, const int* __restrict__ rad,
    float* __restrict__ J)
{
    const int b = blockIdx.y;
    const int y0 = blockIdx.x * CH;
    const int j = threadIdx.x;
    const int r = clamp_r(rad);
    const float inv_kk = 1.0f / (float)((2*r+1) * (2*r+1));
    const float A0 = atm[b*3+0], A1 = atm[b*3+1], A2 = atm[b*3+2];
    const size_t base = (size_t)b * HWn + j;
    const float* imb = img + (size_t)b * 3 * HWn;
    float* Jb = J + (size_t)b * 3 * HWn;

    float s1 = 0.f, s2 = 0.f;
    for (int d = -r; d <= r; ++d) {
        int m = reflect_idx(y0 + d, Hh);
        s1 += ha[base + (size_t)m * Ww];
        s2 += hb[base + (size_t)m * Ww];
    }
    for (int y = y0; y < y0 + CH; ++y) {
        size_t o = base + (size_t)y * Ww;
        float g = gray[o];
        float t = s1 * inv_kk * g + s2 * inv_kk;
        t = fminf(fmaxf(t, 0.1f), 1.0f);
        float invt = 1.0f / (t + 1e-8f);
        size_t po = (size_t)y * Ww + j;
        float v0 = (imb[0*HWn + po] - A0) * invt + A0;
        float v1 = (imb[1*HWn + po] - A1) * invt + A1;
        float v2 = (imb[2*HWn + po] - A2) * invt + A2;
        Jb[0*HWn + po] = fminf(fmaxf(v0, 0.f), 1.f);
        Jb[1*HWn + po] = fminf(fmaxf(v1, 0.f), 1.f);
        Jb[2*HWn + po] = fminf(fmaxf(v2, 0.f), 1.f);
        int yin  = reflect_idx(y + 1 + r, Hh);
        int yout = reflect_idx(y - r, Hh);
        s1 += ha[base + (size_t)yin * Ww] - ha[base + (size_t)yout * Ww];
        s2 += hb[base + (size_t)yin * Ww] - hb[base + (size_t)yout * Ww];
    }
}

// ---------- distributed exact radix select (3 x 10-bit passes) ----------

__global__ __launch_bounds__(256) void k5_zero(unsigned int* __restrict__ p, int n)
{
    int idx = blockIdx.x * 256 + threadIdx.x;
    for (int i = idx; i < n; i += gridDim.x * 256) p[i] = 0u;
}

// pass 1: unfiltered histogram of key>>20 (shared by both targets)
__global__ __launch_bounds__(256) void k5_hist1(
    const float* __restrict__ J, unsigned int* __restrict__ hist1)
{
    const int bc  = blockIdx.x >> 5;
    const int sub = blockIdx.x & (NSUB - 1);
    const int tid = threadIdx.x;
    __shared__ unsigned int h[1024];
    for (int i = tid; i < 1024; i += 256) h[i] = 0u;
    __syncthreads();

    const float4* base = (const float4*)(J + (size_t)bc * HWn) + (size_t)sub * (HWn / 4 / NSUB);
    unsigned int cz = 0, co = 0;
    for (int i = tid; i < HWn / 4 / NSUB; i += 256) {
        float4 v = base[i];
        #pragma unroll
        for (int c = 0; c < 4; ++c) {
            float f = (c == 0) ? v.x : (c == 1) ? v.y : (c == 2) ? v.z : v.w;
            unsigned int key = __float_as_uint(f) & 0x7FFFFFFFu;
            if (key == 0u)           cz++;
            else if (key == ONEBITS) co++;
            else atomicAdd(&h[key >> 20], 1u);
        }
    }
    if (cz) atomicAdd(&h[0], cz);
    if (co) atomicAdd(&h[ONEBITS >> 20], co);
    __syncthreads();
    for (int i = tid; i < 1024; i += 256)
        if (h[i]) atomicAdd(&hist1[bc * 1024 + i], h[i]);
}

// passes 2/3: per-target filtered histogram
__global__ __launch_bounds__(256) void k5_hist(
    const float* __restrict__ J, const unsigned int* __restrict__ prefix_g,
    unsigned int* __restrict__ hist,   // [2][24][1024]
    unsigned int maskHigh, int shift)
{
    const int bc  = blockIdx.x >> 5;
    const int sub = blockIdx.x & (NSUB - 1);
    const int tid = threadIdx.x;
    __shared__ unsigned int h[2][1024];
    for (int i = tid; i < 2048; i += 256) ((unsigned int*)h)[i] = 0u;
    __syncthreads();
    const unsigned int p0 = prefix_g[0 * 24 + bc];
    const unsigned int p1 = prefix_g[1 * 24 + bc];

    const float4* base = (const float4*)(J + (size_t)bc * HWn) + (size_t)sub * (HWn / 4 / NSUB);
    unsigned int cz = 0, co = 0;
    for (int i = tid; i < HWn / 4 / NSUB; i += 256) {
        float4 v = base[i];
        #pragma unroll
        for (int c = 0; c < 4; ++c) {
            float f = (c == 0) ? v.x : (c == 1) ? v.y : (c == 2) ? v.z : v.w;
            unsigned int key = __float_as_uint(f) & 0x7FFFFFFFu;
            if (key == 0u)           { cz++; continue; }
            if (key == ONEBITS)      { co++; continue; }
            unsigned int hi = key & maskHigh;
            unsigned int bin = (key >> shift) & 1023u;
            if (hi == p0) atomicAdd(&h[0][bin], 1u);
            if (hi == p1) atomicAdd(&h[1][bin], 1u);
        }
    }
    if (cz) {
        if (p0 == 0u) atomicAdd(&h[0][0], cz);
        if (p1 == 0u) atomicAdd(&h[1][0], cz);
    }
    if (co) {
        unsigned int bin1 = (ONEBITS >> shift) & 1023u;
        if ((ONEBITS & maskHigh) == p0) atomicAdd(&h[0][bin1], co);
        if ((ONEBITS & maskHigh) == p1) atomicAdd(&h[1][bin1], co);
    }
    __syncthreads();
    for (int i = tid; i < 2048; i += 256) {
        unsigned int v = ((unsigned int*)h)[i];
        if (v) atomicAdd(&hist[bc * 1024 + (i >> 10) * 24 * 1024 + (i & 1023)], v);
    }
}

// decide: one wave per (target, bc). Scans 1024 bins, locates rank bin.
__global__ __launch_bounds__(64) void k5_decide(
    const unsigned int* __restrict__ hist,  // [.][24][1024]
    unsigned int* __restrict__ prefix_g, int* __restrict__ krem,
    const float* __restrict__ L_low, const float* __restrict__ L_high,
    int shift, int first, int last,
    float* __restrict__ p_low, float* __restrict__ p_high)
{
    const int t  = blockIdx.x / 24;
    const int bc = blockIdx.x % 24;
    const int b  = bc / 3;
    const int lane = threadIdx.x;
    const unsigned int* hb = hist + (size_t)(first ? bc : (t * 24 + bc)) * 1024;

    unsigned int loc[16];
    unsigned int lsum = 0;
    #pragma unroll
    for (int i = 0; i < 16; ++i) { loc[i] = hb[lane * 16 + i]; lsum += loc[i]; }

    unsigned int incl = lsum;
    #pragma unroll
    for (int off = 1; off < 64; off <<= 1) {
        unsigned int v = __shfl_up(incl, off);
        if (lane >= off) incl += v;
    }
    unsigned int excl = incl - lsum;

    int k;
    if (first) {
        float L = t ? L_high[b] : L_low[b];
        k = (int)(L * (1.0f / 100.0f) * (float)HWn);
        k = (k < 0) ? 0 : ((k > HWn - 1) ? HWn - 1 : k);
    } else {
        k = krem[t * 24 + bc];
    }

    if ((unsigned int)k >= excl && (unsigned int)k < incl) {
        unsigned int c = excl;
        #pragma unroll
        for (int i = 0; i < 16; ++i) {
            if ((unsigned int)k < c + loc[i]) {
                unsigned int bin = (unsigned int)(lane * 16 + i);
                unsigned int np = (first ? 0u : prefix_g[t * 24 + bc]) | (bin << shift);
                if (last) {
                    if (t) p_high[bc] = __uint_as_float(np);
                    else   p_low[bc]  = __uint_as_float(np);
                } else {
                    prefix_g[t * 24 + bc] = np;
                    krem[t * 24 + bc] = k - (int)c;
                }
                break;
            }
            c += loc[i];
        }
    }
}

// K6: in-place percentile stretch on d_out
__global__ __launch_bounds__(256) void k6_norm(
    float* __restrict__ J,
    const float* __restrict__ p_low, const float* __restrict__ p_high)
{
    size_t idx = (size_t)blockIdx.x * 256 + threadIdx.x;
    int bc = (int)(idx >> 18);           // HWn == 2^18
    float pl = p_low[bc], ph = p_high[bc];
    float v = J[idx];
    v = fminf(fmaxf(v, pl), ph);
    v = (v - pl) / (ph - pl + 1e-8f);
    J[idx] = fminf(fmaxf(v, 0.f), 1.f);
}

extern "C" void kernel_launch(void* const* d_in, const int* in_sizes, int n_in,
                              void* d_out, int out_size, void* d_ws, size_t ws_size,
                              hipStream_t stream)
{
    const float* img    = (const float*)d_in[0];
    const float* omega  = (const float*)d_in[1];
    const float* atm    = (const float*)d_in[2];
    const float* L_low  = (const float*)d_in[3];
    const float* L_high = (const float*)d_in[4];
    const int*   rad    = (const int*)d_in[5];
    float* J  = (float*)d_out;
    float* ws = (float*)d_ws;

    const size_t F = (size_t)Bb * HWn;   // 2097152 floats per field
    float* gray = ws;
    float* h1 = ws + 1*F;
    float* h2 = ws + 2*F;
    float* h3 = ws + 3*F;
    float* h4 = ws + 4*F;
    float* a_ = ws + 5*F;
    float* b_ = ws + 6*F;
    float* ha = h1;   // reuse: h1..h4 dead after K2 (ha/hb overwrite h1/h2)
    float* hb = h2;
    float* pl = ws + 7*F;
    float* ph = pl + 32;

    // radix-select state lives in the h3/h4 regions (dead after K2)
    unsigned int* hist1  = (unsigned int*)h3;                  // [24][1024]
    unsigned int* hist2  = hist1 + 24 * 1024;                  // [2][24][1024]
    unsigned int* hist3  = hist2 + 2 * 24 * 1024;              // [2][24][1024]
    unsigned int* prefix = (unsigned int*)h4;                  // [2][24]
    int*          krem   = (int*)(prefix + 64);                // [2][24]
    const int histTotal  = 24 * 1024 + 2 * 2 * 24 * 1024;      // 122880 uints

    k1_stats_h<<<dim3(Hh, Bb), 512, 0, stream>>>(img, omega, atm, rad, gray, h1, h2, h3, h4);
    k2_stats_v<<<dim3(Hh/CH, Bb), 512, 0, stream>>>(h1, h2, h3, h4, rad, a_, b_);
    k5_zero  <<<120, 256, 0, stream>>>(hist1, histTotal);
    k3_ab_h  <<<dim3(Hh, Bb), 512, 0, stream>>>(a_, b_, rad, ha, hb);
    k4_final_v<<<dim3(Hh/CH, Bb), 512, 0, stream>>>(ha, hb, gray, img, atm, rad, J);

    k5_hist1 <<<24 * NSUB, 256, 0, stream>>>(J, hist1);
    k5_decide<<<48, 64, 0, stream>>>(hist1, prefix, krem, L_low, L_high, 20, 1, 0, pl, ph);
    k5_hist  <<<24 * NSUB, 256, 0, stream>>>(J, prefix, hist2, 0x3FF00000u, 10);
    k5_decide<<<48, 64, 0, stream>>>(hist2, prefix, krem, L_low, L_high, 10, 0, 0, pl, ph);
    k5_hist  <<<24 * NSUB, 256, 0, stream>>>(J, prefix, hist3, 0x3FFFFC00u, 0);
    k5_decide<<<48, 64, 0, stream>>>(hist3, prefix, krem, L_low, L_high, 0, 0, 1, pl, ph);

    k6_norm  <<<(int)(((size_t)Bb*3*HWn)/256), 256, 0, stream>>>(J, pl, ph);
}

// Round 4
// 212.148 us; speedup vs baseline: 2.6836x; 1.0870x over previous
//
#include <hip/hip_runtime.h>
#include <cstdint>

constexpr int Bb = 8, Hh = 512, Ww = 512;
constexpr int HWn = Hh * Ww;          // 262144 = 2^18
constexpr int CH  = 32;               // rows per block in k2
constexpr int CH2 = 16;               // rows per block in k34
constexpr unsigned int ONEBITS = 0x3F800000u;
constexpr int NSUB = 32;              // sub-blocks per (b,c) in hist kernels

__device__ __forceinline__ int reflect_idx(int p, int n) {
    p = (p < 0) ? -p : p;
    return (p < n) ? p : (2 * n - 2 - p);
}
__device__ __forceinline__ int clamp_r(const int* rad) {
    int r = rad[0];
    return (r < 1) ? 1 : ((r > 50) ? 50 : r);
}

// ---------------- K1: rows -> horizontal box sums (float4) ----------------
// prefix-scan box filter: per row, inclusive prefix P of (g,t,g*t,g*g), then
// box(j) = P[min(j+r,511)] - (j-r>0 ? P[j-r-1] : 0)
//        + (j<r      ? P[r-j]  - P[0]        : 0)     // left reflect
//        + (j+r>511  ? P[510]  - P[1021-j-r] : 0)     // right reflect
__global__ __launch_bounds__(512) void k1_stats_h(
    const float* __restrict__ img, const float* __restrict__ omega,
    const float* __restrict__ atm, const int* __restrict__ rad,
    float4* __restrict__ hq, unsigned int* __restrict__ histzero)
{
    const int i = blockIdx.x;
    const int b = blockIdx.y;
    const int j = threadIdx.x;           // 512 threads = one per column
    const int fbid = b * gridDim.x + i;
    if (fbid < 240) histzero[fbid * 512 + j] = 0u;   // zero radix-select state
    const int r = clamp_r(rad);

    __shared__ float t0c[512], t0p[512];
    __shared__ float4 Pb[512];
    __shared__ float4 wsum[8];

    const float om = omega[b];
    const float iA0 = 1.0f / (atm[b*3+0] + 1e-8f);
    const float iA1 = 1.0f / (atm[b*3+1] + 1e-8f);
    const float iA2 = 1.0f / (atm[b*3+2] + 1e-8f);
    const float* imb = img + (size_t)b * 3 * HWn;
    const int ip = (i > 0) ? (i - 1) : 0;

    float r0 = imb[0*HWn + i*Ww + j];
    float g0 = imb[1*HWn + i*Ww + j];
    float b0 = imb[2*HWn + i*Ww + j];
    t0c[j] = 1.0f - om * fminf(fminf(r0*iA0, g0*iA1), b0*iA2);
    float r1 = imb[0*HWn + ip*Ww + j];
    float g1 = imb[1*HWn + ip*Ww + j];
    float b1 = imb[2*HWn + ip*Ww + j];
    t0p[j] = 1.0f - om * fminf(fminf(r1*iA0, g1*iA1), b1*iA2);
    float gr = 0.299f*r0 + 0.587f*g0 + 0.114f*b0;
    __syncthreads();

    float tx = (j == 0) ? t0p[0] : t0p[j-1] * __expf(-fabsf(t0p[j] - t0p[j-1]));
    float tgv = (i == 0) ? tx : tx * __expf(-fabsf(t0c[j] - t0p[j]));

    // wave-level inclusive scan of float4
    const int lane = j & 63, wv = j >> 6;
    float4 incl;
    incl.x = gr; incl.y = tgv; incl.z = gr * tgv; incl.w = gr * gr;
    #pragma unroll
    for (int off = 1; off < 64; off <<= 1) {
        float ux = __shfl_up(incl.x, off);
        float uy = __shfl_up(incl.y, off);
        float uz = __shfl_up(incl.z, off);
        float uw = __shfl_up(incl.w, off);
        if (lane >= off) { incl.x += ux; incl.y += uy; incl.z += uz; incl.w += uw; }
    }
    if (lane == 63) wsum[wv] = incl;
    __syncthreads();
    float4 o4; o4.x = 0.f; o4.y = 0.f; o4.z = 0.f; o4.w = 0.f;
    #pragma unroll
    for (int w = 0; w < 7; ++w) {
        if (w < wv) {
            float4 t = wsum[w];
            o4.x += t.x; o4.y += t.y; o4.z += t.z; o4.w += t.w;
        }
    }
    float4 P; P.x = incl.x + o4.x; P.y = incl.y + o4.y; P.z = incl.z + o4.z; P.w = incl.w + o4.w;
    Pb[j] = P;
    __syncthreads();

    const int lo = j - r, hi = j + r;
    float4 s = Pb[(hi > 511) ? 511 : hi];
    if (lo > 0) {
        float4 t = Pb[lo-1];
        s.x -= t.x; s.y -= t.y; s.z -= t.z; s.w -= t.w;
    }
    if (lo < 0) {
        float4 t = Pb[r - j], u = Pb[0];
        s.x += t.x - u.x; s.y += t.y - u.y; s.z += t.z - u.z; s.w += t.w - u.w;
    }
    if (hi > 511) {
        float4 t = Pb[510], u = Pb[1021 - j - r];
        s.x += t.x - u.x; s.y += t.y - u.y; s.z += t.z - u.z; s.w += t.w - u.w;
    }
    hq[((size_t)b * Hh + i) * Ww + j] = s;
}

// ---------------- K2: vertical sliding box on hq -> a,b (float2) ----------
__global__ __launch_bounds__(256) void k2_stats_v(
    const float4* __restrict__ hq, const int* __restrict__ rad,
    float2* __restrict__ ab)
{
    const int b  = blockIdx.y;
    const int y0 = blockIdx.x * CH;
    const int j  = blockIdx.z * 256 + threadIdx.x;
    const int r  = clamp_r(rad);
    const float ikk = 1.0f / (float)((2*r+1) * (2*r+1));

    float4 s; s.x = 0.f; s.y = 0.f; s.z = 0.f; s.w = 0.f;
    for (int d = -r; d <= r; ++d) {
        int m = reflect_idx(y0 + d, Hh);
        float4 v = hq[((size_t)b * Hh + m) * Ww + j];
        s.x += v.x; s.y += v.y; s.z += v.z; s.w += v.w;
    }
    for (int y = y0; y < y0 + CH; ++y) {
        float mI = s.x * ikk, mp = s.y * ikk, mIp = s.z * ikk, mII = s.w * ikk;
        float av = (mIp - mI * mp) / (mII - mI * mI + 0.5f);
        float bv = mp - av * mI;
        float2 o; o.x = av; o.y = bv;
        ab[((size_t)b * Hh + y) * Ww + j] = o;
        int yin  = reflect_idx(y + 1 + r, Hh);
        int yout = reflect_idx(y - r, Hh);
        float4 vi = hq[((size_t)b * Hh + yin)  * Ww + j];
        float4 vo = hq[((size_t)b * Hh + yout) * Ww + j];
        s.x += vi.x - vo.x; s.y += vi.y - vo.y; s.z += vi.z - vo.z; s.w += vi.w - vo.w;
    }
}

// ---- K34: vertical running sums of a,b + per-row prefix box -> t -> J ----
// also accumulates pass-1 radix histograms (key>>20) per channel.
__global__ __launch_bounds__(512) void k34_final(
    const float2* __restrict__ ab, const float* __restrict__ img,
    const float* __restrict__ atm, const int* __restrict__ rad,
    float* __restrict__ J, unsigned int* __restrict__ hist1)
{
    const int b  = blockIdx.y;
    const int y0 = blockIdx.x * CH2;
    const int j  = threadIdx.x;
    const int r  = clamp_r(rad);
    const float ikk = 1.0f / (float)((2*r+1) * (2*r+1));
    const int lane = j & 63, wv = j >> 6;

    __shared__ float2 Pb[512];
    __shared__ float2 wsum[8];
    __shared__ unsigned int lh[3 * 1024];
    for (int t = j; t < 3072; t += 512) lh[t] = 0u;

    float Aa[3];
    Aa[0] = atm[b*3+0]; Aa[1] = atm[b*3+1]; Aa[2] = atm[b*3+2];
    const float* imb = img + (size_t)b * 3 * HWn;
    float* Jb = J + (size_t)b * 3 * HWn;

    float2 V; V.x = 0.f; V.y = 0.f;
    for (int d = -r; d <= r; ++d) {
        int m = reflect_idx(y0 + d, Hh);
        float2 v = ab[((size_t)b * Hh + m) * Ww + j];
        V.x += v.x; V.y += v.y;
    }
    unsigned int cz[3] = {0u,0u,0u}, co[3] = {0u,0u,0u};

    for (int y = y0; y < y0 + CH2; ++y) {
        float2 incl = V;
        #pragma unroll
        for (int off = 1; off < 64; off <<= 1) {
            float ux = __shfl_up(incl.x, off);
            float uy = __shfl_up(incl.y, off);
            if (lane >= off) { incl.x += ux; incl.y += uy; }
        }
        if (lane == 63) wsum[wv] = incl;
        __syncthreads();
        float ox = 0.f, oy = 0.f;
        #pragma unroll
        for (int w = 0; w < 7; ++w) {
            if (w < wv) { float2 t = wsum[w]; ox += t.x; oy += t.y; }
        }
        float2 P; P.x = incl.x + ox; P.y = incl.y + oy;
        Pb[j] = P;
        __syncthreads();

        const int lo = j - r, hi = j + r;
        float2 s = Pb[(hi > 511) ? 511 : hi];
        if (lo > 0)   { float2 t = Pb[lo-1];  s.x -= t.x; s.y -= t.y; }
        if (lo < 0)   { float2 t = Pb[r-j], u = Pb[0];
                        s.x += t.x - u.x; s.y += t.y - u.y; }
        if (hi > 511) { float2 t = Pb[510], u = Pb[1021-j-r];
                        s.x += t.x - u.x; s.y += t.y - u.y; }

        const size_t po = (size_t)y * Ww + j;
        float cc[3];
        cc[0] = imb[0*HWn + po]; cc[1] = imb[1*HWn + po]; cc[2] = imb[2*HWn + po];
        float g = 0.299f*cc[0] + 0.587f*cc[1] + 0.114f*cc[2];
        float t = fminf(fmaxf((s.x * g + s.y) * ikk, 0.1f), 1.0f);
        float invt = 1.0f / (t + 1e-8f);
        #pragma unroll
        for (int c = 0; c < 3; ++c) {
            float v = fminf(fmaxf((cc[c] - Aa[c]) * invt + Aa[c], 0.f), 1.f);
            Jb[c*HWn + po] = v;
            unsigned int key = __float_as_uint(v);
            if (key == 0u)           cz[c]++;
            else if (key == ONEBITS) co[c]++;
            else atomicAdd(&lh[c*1024 + (key >> 20)], 1u);
        }
        int yin  = reflect_idx(y + 1 + r, Hh);
        int yout = reflect_idx(y - r, Hh);
        float2 vi = ab[((size_t)b * Hh + yin)  * Ww + j];
        float2 vo = ab[((size_t)b * Hh + yout) * Ww + j];
        V.x += vi.x - vo.x; V.y += vi.y - vo.y;
        __syncthreads();
    }
    #pragma unroll
    for (int c = 0; c < 3; ++c) {
        if (cz[c]) atomicAdd(&lh[c*1024 + 0], cz[c]);
        if (co[c]) atomicAdd(&lh[c*1024 + (ONEBITS >> 20)], co[c]);
    }
    __syncthreads();
    for (int t = j; t < 3072; t += 512) {
        unsigned int v = lh[t];
        if (v) atomicAdd(&hist1[(size_t)b * 3 * 1024 + t], v);
    }
}

// ---------- distributed exact radix select: passes 2/3 ----------
__global__ __launch_bounds__(256) void k5_hist(
    const float* __restrict__ J, const unsigned int* __restrict__ prefix_g,
    unsigned int* __restrict__ hist,   // [2][24][1024]
    unsigned int maskHigh, int shift)
{
    const int bc  = blockIdx.x >> 5;
    const int sub = blockIdx.x & (NSUB - 1);
    const int tid = threadIdx.x;
    __shared__ unsigned int h[2][1024];
    for (int i = tid; i < 2048; i += 256) ((unsigned int*)h)[i] = 0u;
    __syncthreads();
    const unsigned int p0 = prefix_g[0 * 24 + bc];
    const unsigned int p1 = prefix_g[1 * 24 + bc];

    const float4* base = (const float4*)(J + (size_t)bc * HWn) + (size_t)sub * (HWn / 4 / NSUB);
    unsigned int cz = 0, co = 0;
    for (int i = tid; i < HWn / 4 / NSUB; i += 256) {
        float4 v = base[i];
        #pragma unroll
        for (int c = 0; c < 4; ++c) {
            float f = (c == 0) ? v.x : (c == 1) ? v.y : (c == 2) ? v.z : v.w;
            unsigned int key = __float_as_uint(f) & 0x7FFFFFFFu;
            if (key == 0u)           { cz++; continue; }
            if (key == ONEBITS)      { co++; continue; }
            unsigned int hi = key & maskHigh;
            unsigned int bin = (key >> shift) & 1023u;
            if (hi == p0) atomicAdd(&h[0][bin], 1u);
            if (hi == p1) atomicAdd(&h[1][bin], 1u);
        }
    }
    if (cz) {
        if (p0 == 0u) atomicAdd(&h[0][0], cz);
        if (p1 == 0u) atomicAdd(&h[1][0], cz);
    }
    if (co) {
        unsigned int bin1 = (ONEBITS >> shift) & 1023u;
        if ((ONEBITS & maskHigh) == p0) atomicAdd(&h[0][bin1], co);
        if ((ONEBITS & maskHigh) == p1) atomicAdd(&h[1][bin1], co);
    }
    __syncthreads();
    for (int i = tid; i < 2048; i += 256) {
        unsigned int v = ((unsigned int*)h)[i];
        if (v) atomicAdd(&hist[bc * 1024 + (i >> 10) * 24 * 1024 + (i & 1023)], v);
    }
}

// decide: one wave per (target, bc). Scans 1024 bins, locates rank bin.
__global__ __launch_bounds__(64) void k5_decide(
    const unsigned int* __restrict__ hist,  // [.][24][1024]
    unsigned int* __restrict__ prefix_g, int* __restrict__ krem,
    const float* __restrict__ L_low, const float* __restrict__ L_high,
    int shift, int first, int last,
    float* __restrict__ p_low, float* __restrict__ p_high)
{
    const int t  = blockIdx.x / 24;
    const int bc = blockIdx.x % 24;
    const int b  = bc / 3;
    const int lane = threadIdx.x;
    const unsigned int* hb = hist + (size_t)(first ? bc : (t * 24 + bc)) * 1024;

    unsigned int loc[16];
    unsigned int lsum = 0;
    #pragma unroll
    for (int i = 0; i < 16; ++i) { loc[i] = hb[lane * 16 + i]; lsum += loc[i]; }

    unsigned int incl = lsum;
    #pragma unroll
    for (int off = 1; off < 64; off <<= 1) {
        unsigned int v = __shfl_up(incl, off);
        if (lane >= off) incl += v;
    }
    unsigned int excl = incl - lsum;

    int k;
    if (first) {
        float L = t ? L_high[b] : L_low[b];
        k = (int)(L * (1.0f / 100.0f) * (float)HWn);
        k = (k < 0) ? 0 : ((k > HWn - 1) ? HWn - 1 : k);
    } else {
        k = krem[t * 24 + bc];
    }

    if ((unsigned int)k >= excl && (unsigned int)k < incl) {
        unsigned int c = excl;
        #pragma unroll
        for (int i = 0; i < 16; ++i) {
            if ((unsigned int)k < c + loc[i]) {
                unsigned int bin = (unsigned int)(lane * 16 + i);
                unsigned int np = (first ? 0u : prefix_g[t * 24 + bc]) | (bin << shift);
                if (last) {
                    if (t) p_high[bc] = __uint_as_float(np);
                    else   p_low[bc]  = __uint_as_float(np);
                } else {
                    prefix_g[t * 24 + bc] = np;
                    krem[t * 24 + bc] = k - (int)c;
                }
                break;
            }
            c += loc[i];
        }
    }
}

// ---------------- K6: in-place percentile stretch (float4) ----------------
__global__ __launch_bounds__(256) void k6_norm(
    float4* __restrict__ J,
    const float* __restrict__ p_low, const float* __restrict__ p_high)
{
    size_t idx = (size_t)blockIdx.x * 256 + threadIdx.x;
    int bc = (int)(idx >> 16);           // HWn/4 == 2^16 float4s per (b,c)
    float l = p_low[bc], h = p_high[bc];
    float inv = 1.0f / (h - l + 1e-8f);
    float4 v = J[idx];
    v.x = fminf(fmaxf((fminf(fmaxf(v.x, l), h) - l) * inv, 0.f), 1.f);
    v.y = fminf(fmaxf((fminf(fmaxf(v.y, l), h) - l) * inv, 0.f), 1.f);
    v.z = fminf(fmaxf((fminf(fmaxf(v.z, l), h) - l) * inv, 0.f), 1.f);
    v.w = fminf(fmaxf((fminf(fmaxf(v.w, l), h) - l) * inv, 0.f), 1.f);
    J[idx] = v;
}

extern "C" void kernel_launch(void* const* d_in, const int* in_sizes, int n_in,
                              void* d_out, int out_size, void* d_ws, size_t ws_size,
                              hipStream_t stream)
{
    const float* img    = (const float*)d_in[0];
    const float* omega  = (const float*)d_in[1];
    const float* atm    = (const float*)d_in[2];
    const float* L_low  = (const float*)d_in[3];
    const float* L_high = (const float*)d_in[4];
    const int*   rad    = (const int*)d_in[5];
    float* J  = (float*)d_out;
    float* ws = (float*)d_ws;

    const size_t F = (size_t)Bb * HWn;           // 2097152 px per field
    float4* hq = (float4*)ws;                    // F float4s  (32 MB)
    float2* ab = (float2*)(ws + 4 * F);          // F float2s  (16 MB)
    unsigned int* hist1  = (unsigned int*)(ws + 6 * F);   // [24][1024]
    unsigned int* hist2  = hist1 + 24 * 1024;             // [2][24][1024]
    unsigned int* hist3  = hist2 + 2 * 24 * 1024;         // [2][24][1024]
    unsigned int* prefix = hist3 + 2 * 24 * 1024;         // [2][24]
    int*          krem   = (int*)(prefix + 64);           // [2][24]
    float* pl = (float*)(krem + 64);
    float* ph = pl + 32;
    // note: k1 zeroes hist1..hist3 (240*512 = 122880 uints) as a side duty.

    k1_stats_h<<<dim3(Hh, Bb), 512, 0, stream>>>(img, omega, atm, rad, hq, hist1);
    k2_stats_v<<<dim3(Hh/CH, Bb, 2), 256, 0, stream>>>(hq, rad, ab);
    k34_final <<<dim3(Hh/CH2, Bb), 512, 0, stream>>>(ab, img, atm, rad, J, hist1);

    k5_decide<<<48, 64, 0, stream>>>(hist1, prefix, krem, L_low, L_high, 20, 1, 0, pl, ph);
    k5_hist  <<<24 * NSUB, 256, 0, stream>>>(J, prefix, hist2, 0x3FF00000u, 10);
    k5_decide<<<48, 64, 0, stream>>>(hist2, prefix, krem, L_low, L_high, 10, 0, 0, pl, ph);
    k5_hist  <<<24 * NSUB, 256, 0, stream>>>(J, prefix, hist3, 0x3FFFFC00u, 0);
    k5_decide<<<48, 64, 0, stream>>>(hist3, prefix, krem, L_low, L_high, 0, 0, 1, pl, ph);

    // 3*F floats in J -> 3*F/4 float4s -> /256 threads per block
    k6_norm  <<<(int)(3 * F / 4 / 256), 256, 0, stream>>>((float4*)J, pl, ph);
}

// Round 5
// 181.952 us; speedup vs baseline: 3.1289x; 1.1660x over previous
//
#include <hip/hip_runtime.h>
#include <cstdint>

constexpr int Bb = 8, Hh = 512, Ww = 512;
constexpr int HWn = Hh * Ww;          // 262144 = 2^18
constexpr int CHK2 = 16;              // rows per block in k2 (vertical sliding)
constexpr int CHK4 = 16;              // rows per block in k4 (vertical sliding)
constexpr int NBIN = 2048;            // percentile histogram bins over [0,1]

__device__ __forceinline__ int reflect_idx(int p, int n) {
    p = (p < 0) ? -p : p;
    return (p < n) ? p : (2 * n - 2 - p);
}
__device__ __forceinline__ int clamp_r(const int* rad) {
    int r = rad[0];
    return (r < 1) ? 1 : ((r > 50) ? 50 : r);
}

// ---------------- K1: rows -> horizontal box sums (float4) ----------------
// prefix-scan box filter: per row, inclusive prefix P of (g,t,g*t,g*g), then
// box(j) = P[min(j+r,511)] - (j-r>0 ? P[j-r-1] : 0)
//        + (j<r      ? P[r-j]  - P[0]        : 0)     // left reflect
//        + (j+r>511  ? P[510]  - P[1021-j-r] : 0)     // right reflect
__global__ __launch_bounds__(512) void k1_stats_h(
    const float* __restrict__ img, const float* __restrict__ omega,
    const float* __restrict__ atm, const int* __restrict__ rad,
    float4* __restrict__ hq, unsigned int* __restrict__ histzero)
{
    const int i = blockIdx.x;
    const int b = blockIdx.y;
    const int j = threadIdx.x;           // 512 threads = one per column
    const int fbid = b * gridDim.x + i;
    if (fbid < 96) histzero[fbid * 512 + j] = 0u;   // zero 24*2048 hist bins
    const int r = clamp_r(rad);

    __shared__ float t0c[512], t0p[512];
    __shared__ float4 Pb[512];
    __shared__ float4 wsum[8];

    const float om = omega[b];
    const float iA0 = 1.0f / (atm[b*3+0] + 1e-8f);
    const float iA1 = 1.0f / (atm[b*3+1] + 1e-8f);
    const float iA2 = 1.0f / (atm[b*3+2] + 1e-8f);
    const float* imb = img + (size_t)b * 3 * HWn;
    const int ip = (i > 0) ? (i - 1) : 0;

    float r0 = imb[0*HWn + i*Ww + j];
    float g0 = imb[1*HWn + i*Ww + j];
    float b0 = imb[2*HWn + i*Ww + j];
    t0c[j] = 1.0f - om * fminf(fminf(r0*iA0, g0*iA1), b0*iA2);
    float r1 = imb[0*HWn + ip*Ww + j];
    float g1 = imb[1*HWn + ip*Ww + j];
    float b1 = imb[2*HWn + ip*Ww + j];
    t0p[j] = 1.0f - om * fminf(fminf(r1*iA0, g1*iA1), b1*iA2);
    float gr = 0.299f*r0 + 0.587f*g0 + 0.114f*b0;
    __syncthreads();

    float tx = (j == 0) ? t0p[0] : t0p[j-1] * __expf(-fabsf(t0p[j] - t0p[j-1]));
    float tgv = (i == 0) ? tx : tx * __expf(-fabsf(t0c[j] - t0p[j]));

    // wave-level inclusive scan of float4
    const int lane = j & 63, wv = j >> 6;
    float4 incl;
    incl.x = gr; incl.y = tgv; incl.z = gr * tgv; incl.w = gr * gr;
    #pragma unroll
    for (int off = 1; off < 64; off <<= 1) {
        float ux = __shfl_up(incl.x, off);
        float uy = __shfl_up(incl.y, off);
        float uz = __shfl_up(incl.z, off);
        float uw = __shfl_up(incl.w, off);
        if (lane >= off) { incl.x += ux; incl.y += uy; incl.z += uz; incl.w += uw; }
    }
    if (lane == 63) wsum[wv] = incl;
    __syncthreads();
    float4 o4; o4.x = 0.f; o4.y = 0.f; o4.z = 0.f; o4.w = 0.f;
    #pragma unroll
    for (int w = 0; w < 7; ++w) {
        if (w < wv) {
            float4 t = wsum[w];
            o4.x += t.x; o4.y += t.y; o4.z += t.z; o4.w += t.w;
        }
    }
    float4 P; P.x = incl.x + o4.x; P.y = incl.y + o4.y; P.z = incl.z + o4.z; P.w = incl.w + o4.w;
    Pb[j] = P;
    __syncthreads();

    const int lo = j - r, hi = j + r;
    float4 s = Pb[(hi > 511) ? 511 : hi];
    if (lo > 0) {
        float4 t = Pb[lo-1];
        s.x -= t.x; s.y -= t.y; s.z -= t.z; s.w -= t.w;
    }
    if (lo < 0) {
        float4 t = Pb[r - j], u = Pb[0];
        s.x += t.x - u.x; s.y += t.y - u.y; s.z += t.z - u.z; s.w += t.w - u.w;
    }
    if (hi > 511) {
        float4 t = Pb[510], u = Pb[1021 - j - r];
        s.x += t.x - u.x; s.y += t.y - u.y; s.z += t.z - u.z; s.w += t.w - u.w;
    }
    hq[((size_t)b * Hh + i) * Ww + j] = s;
}

// ---------------- K2: vertical sliding box on hq -> a,b (float2) ----------
__global__ __launch_bounds__(256) void k2_stats_v(
    const float4* __restrict__ hq, const int* __restrict__ rad,
    float2* __restrict__ ab)
{
    const int b  = blockIdx.y;
    const int y0 = blockIdx.x * CHK2;
    const int j  = blockIdx.z * 256 + threadIdx.x;
    const int r  = clamp_r(rad);
    const float ikk = 1.0f / (float)((2*r+1) * (2*r+1));

    float4 s; s.x = 0.f; s.y = 0.f; s.z = 0.f; s.w = 0.f;
    for (int d = -r; d <= r; ++d) {
        int m = reflect_idx(y0 + d, Hh);
        float4 v = hq[((size_t)b * Hh + m) * Ww + j];
        s.x += v.x; s.y += v.y; s.z += v.z; s.w += v.w;
    }
    for (int y = y0; y < y0 + CHK2; ++y) {
        float mI = s.x * ikk, mp = s.y * ikk, mIp = s.z * ikk, mII = s.w * ikk;
        float av = (mIp - mI * mp) / (mII - mI * mI + 0.5f);
        float bv = mp - av * mI;
        float2 o; o.x = av; o.y = bv;
        ab[((size_t)b * Hh + y) * Ww + j] = o;
        int yin  = reflect_idx(y + 1 + r, Hh);
        int yout = reflect_idx(y - r, Hh);
        float4 vi = hq[((size_t)b * Hh + yin)  * Ww + j];
        float4 vo = hq[((size_t)b * Hh + yout) * Ww + j];
        s.x += vi.x - vo.x; s.y += vi.y - vo.y; s.z += vi.z - vo.z; s.w += vi.w - vo.w;
    }
}

// ------------- K3: horizontal box sums of a,b via per-row prefix ----------
__global__ __launch_bounds__(512) void k3_ab_h(
    const float2* __restrict__ ab, const int* __restrict__ rad,
    float2* __restrict__ hab)
{
    const int i = blockIdx.x;
    const int b = blockIdx.y;
    const int j = threadIdx.x;
    const int r = clamp_r(rad);
    const int lane = j & 63, wv = j >> 6;

    __shared__ float2 Pb[512];
    __shared__ float2 wsum[8];

    float2 v = ab[((size_t)b * Hh + i) * Ww + j];
    float2 incl = v;
    #pragma unroll
    for (int off = 1; off < 64; off <<= 1) {
        float ux = __shfl_up(incl.x, off);
        float uy = __shfl_up(incl.y, off);
        if (lane >= off) { incl.x += ux; incl.y += uy; }
    }
    if (lane == 63) wsum[wv] = incl;
    __syncthreads();
    float ox = 0.f, oy = 0.f;
    #pragma unroll
    for (int w = 0; w < 7; ++w) {
        if (w < wv) { float2 t = wsum[w]; ox += t.x; oy += t.y; }
    }
    float2 P; P.x = incl.x + ox; P.y = incl.y + oy;
    Pb[j] = P;
    __syncthreads();

    const int lo = j - r, hi = j + r;
    float2 s = Pb[(hi > 511) ? 511 : hi];
    if (lo > 0)   { float2 t = Pb[lo-1];  s.x -= t.x; s.y -= t.y; }
    if (lo < 0)   { float2 t = Pb[r-j], u = Pb[0];
                    s.x += t.x - u.x; s.y += t.y - u.y; }
    if (hi > 511) { float2 t = Pb[510], u = Pb[1021-j-r];
                    s.x += t.x - u.x; s.y += t.y - u.y; }
    hab[((size_t)b * Hh + i) * Ww + j] = s;
}

// ---- K4: vertical sliding box on hab -> t -> J + 2048-bin histogram ------
// no __syncthreads in the main loop (pure sliding + pointwise).
__global__ __launch_bounds__(256) void k4_final_v(
    const float2* __restrict__ hab, const float* __restrict__ img,
    const float* __restrict__ atm, const int* __restrict__ rad,
    float* __restrict__ J, unsigned int* __restrict__ hist)
{
    const int b  = blockIdx.y;
    const int y0 = blockIdx.x * CHK4;
    const int j  = blockIdx.z * 256 + threadIdx.x;
    const int tid = threadIdx.x;
    const int r  = clamp_r(rad);
    const float ikk = 1.0f / (float)((2*r+1) * (2*r+1));

    __shared__ unsigned int lh[3][NBIN];
    for (int t = tid; t < 3 * NBIN; t += 256) ((unsigned int*)lh)[t] = 0u;
    __syncthreads();

    float Aa[3];
    Aa[0] = atm[b*3+0]; Aa[1] = atm[b*3+1]; Aa[2] = atm[b*3+2];
    const float* imb = img + (size_t)b * 3 * HWn;
    float* Jb = J + (size_t)b * 3 * HWn;

    float2 V; V.x = 0.f; V.y = 0.f;
    for (int d = -r; d <= r; ++d) {
        int m = reflect_idx(y0 + d, Hh);
        float2 v = hab[((size_t)b * Hh + m) * Ww + j];
        V.x += v.x; V.y += v.y;
    }
    unsigned int clo[3] = {0u,0u,0u}, chi[3] = {0u,0u,0u};

    for (int y = y0; y < y0 + CHK4; ++y) {
        const size_t po = (size_t)y * Ww + j;
        float cc[3];
        cc[0] = imb[0*HWn + po]; cc[1] = imb[1*HWn + po]; cc[2] = imb[2*HWn + po];
        float g = 0.299f*cc[0] + 0.587f*cc[1] + 0.114f*cc[2];
        float t = fminf(fmaxf((V.x * g + V.y) * ikk, 0.1f), 1.0f);
        float invt = 1.0f / (t + 1e-8f);
        #pragma unroll
        for (int c = 0; c < 3; ++c) {
            float v = fminf(fmaxf((cc[c] - Aa[c]) * invt + Aa[c], 0.f), 1.f);
            Jb[c*HWn + po] = v;
            int bin = (int)(v * (float)NBIN);
            bin = (bin > NBIN-1) ? NBIN-1 : bin;
            if (bin == 0)            clo[c]++;
            else if (bin == NBIN-1)  chi[c]++;
            else atomicAdd(&lh[c][bin], 1u);
        }
        int yin  = reflect_idx(y + 1 + r, Hh);
        int yout = reflect_idx(y - r, Hh);
        float2 vi = hab[((size_t)b * Hh + yin)  * Ww + j];
        float2 vo = hab[((size_t)b * Hh + yout) * Ww + j];
        V.x += vi.x - vo.x; V.y += vi.y - vo.y;
    }
    #pragma unroll
    for (int c = 0; c < 3; ++c) {
        if (clo[c]) atomicAdd(&lh[c][0], clo[c]);
        if (chi[c]) atomicAdd(&lh[c][NBIN-1], chi[c]);
    }
    __syncthreads();
    for (int t = tid; t < 3 * NBIN; t += 256) {
        unsigned int v = ((unsigned int*)lh)[t];
        if (v) atomicAdd(&hist[(size_t)b * 3 * NBIN + t], v);
    }
}

// ---- K5: one wave per (target,bc): rank -> bin -> percentile value -------
__global__ __launch_bounds__(64) void k5_decide(
    const unsigned int* __restrict__ hist,      // [24][NBIN]
    const float* __restrict__ L_low, const float* __restrict__ L_high,
    float* __restrict__ p_low, float* __restrict__ p_high)
{
    const int t  = blockIdx.x / 24;
    const int bc = blockIdx.x % 24;
    const int b  = bc / 3;
    const int lane = threadIdx.x;
    const unsigned int* hb = hist + (size_t)bc * NBIN;

    unsigned int loc[NBIN / 64];
    unsigned int lsum = 0;
    #pragma unroll
    for (int i = 0; i < NBIN / 64; ++i) { loc[i] = hb[lane * (NBIN/64) + i]; lsum += loc[i]; }

    unsigned int incl = lsum;
    #pragma unroll
    for (int off = 1; off < 64; off <<= 1) {
        unsigned int v = __shfl_up(incl, off);
        if (lane >= off) incl += v;
    }
    unsigned int excl = incl - lsum;

    float L = t ? L_high[b] : L_low[b];
    int k = (int)(L * (1.0f / 100.0f) * (float)HWn);
    k = (k < 0) ? 0 : ((k > HWn - 1) ? HWn - 1 : k);

    if ((unsigned int)k >= excl && (unsigned int)k < incl) {
        unsigned int c = excl;
        #pragma unroll
        for (int i = 0; i < NBIN / 64; ++i) {
            if ((unsigned int)k < c + loc[i]) {
                float val = ((float)(lane * (NBIN/64) + i) + 0.5f) * (1.0f / (float)NBIN);
                if (t) p_high[bc] = val;
                else   p_low[bc]  = val;
                break;
            }
            c += loc[i];
        }
    }
}

// ---------------- K6: in-place percentile stretch (float4) ----------------
__global__ __launch_bounds__(256) void k6_norm(
    float4* __restrict__ J,
    const float* __restrict__ p_low, const float* __restrict__ p_high)
{
    size_t idx = (size_t)blockIdx.x * 256 + threadIdx.x;
    int bc = (int)(idx >> 16);           // HWn/4 == 2^16 float4s per (b,c)
    float l = p_low[bc], h = p_high[bc];
    float inv = 1.0f / (h - l + 1e-8f);
    float4 v = J[idx];
    v.x = fminf(fmaxf((fminf(fmaxf(v.x, l), h) - l) * inv, 0.f), 1.f);
    v.y = fminf(fmaxf((fminf(fmaxf(v.y, l), h) - l) * inv, 0.f), 1.f);
    v.z = fminf(fmaxf((fminf(fmaxf(v.z, l), h) - l) * inv, 0.f), 1.f);
    v.w = fminf(fmaxf((fminf(fmaxf(v.w, l), h) - l) * inv, 0.f), 1.f);
    J[idx] = v;
}

extern "C" void kernel_launch(void* const* d_in, const int* in_sizes, int n_in,
                              void* d_out, int out_size, void* d_ws, size_t ws_size,
                              hipStream_t stream)
{
    const float* img    = (const float*)d_in[0];
    const float* omega  = (const float*)d_in[1];
    const float* atm    = (const float*)d_in[2];
    const float* L_low  = (const float*)d_in[3];
    const float* L_high = (const float*)d_in[4];
    const int*   rad    = (const int*)d_in[5];
    float* J  = (float*)d_out;
    float* ws = (float*)d_ws;

    const size_t F = (size_t)Bb * HWn;           // 2097152 px per field
    float4* hq  = (float4*)ws;                   // [0,4F) floats (32 MB)
    float2* ab  = (float2*)(ws + 4 * F);         // [4F,6F)      (16 MB)
    float2* hab = (float2*)ws;                   // reuse [0,2F) — hq dead after k2
    unsigned int* hist = (unsigned int*)(ws + 6 * F);   // [24][2048]
    float* pl = (float*)(hist + 24 * NBIN);
    float* ph = pl + 32;
    // k1 zeroes hist (96*512 = 49152 = 24*2048 uints) as a side duty.

    k1_stats_h<<<dim3(Hh, Bb), 512, 0, stream>>>(img, omega, atm, rad, hq, hist);
    k2_stats_v<<<dim3(Hh/CHK2, Bb, 2), 256, 0, stream>>>(hq, rad, ab);
    k3_ab_h   <<<dim3(Hh, Bb), 512, 0, stream>>>(ab, rad, hab);
    k4_final_v<<<dim3(Hh/CHK4, Bb, 2), 256, 0, stream>>>(hab, img, atm, rad, J, hist);
    k5_decide <<<48, 64, 0, stream>>>(hist, L_low, L_high, pl, ph);
    k6_norm   <<<(int)(3 * F / 4 / 256), 256, 0, stream>>>((float4*)J, pl, ph);
}